// Round 7
// baseline (232.540 us; speedup 1.0000x reference)
//
#include <hip/hip_runtime.h>

// B=64, N=2048, DIM_IN=DIM_OUT=64, CHEB_K=3, EMBED_DIM=10
#define NN 2048
#define BB 64
#define CC 64
#define ED 10
#define KK 3
#define JJ (BB * CC)   // 4096

typedef unsigned short ushort_t;
typedef __attribute__((ext_vector_type(8))) short short8;   // 8 bf16 = 4 VGPRs
typedef __attribute__((ext_vector_type(4))) float f32x4;

typedef const __attribute__((address_space(1))) unsigned* gptr_t;
typedef __attribute__((address_space(3))) unsigned* lptr_t;

static __device__ __forceinline__ ushort_t f2bf(float f) {
    union { float f; unsigned u; } x{f};
    unsigned r = x.u + 0x7FFF + ((x.u >> 16) & 1);  // RTN-even
    return (ushort_t)(r >> 16);
}
static __device__ __forceinline__ float bf2f(ushort_t h) {
    union { unsigned u; float f; } x;
    x.u = ((unsigned)h) << 16;
    return x.f;
}

// ---------------------------------------------------------------------------
// Kernel 1 (merged prep): blockIdx selects role.
//   [0, NN)            : supports — A_bf16[n][m] = softmax(relu(E E^T)) row n
//   [NN, 2*NN)         : transpose — x[b][n][c] -> xT[(b*64+c)][n], xN[n][j]
//   [2*NN, 2*NN+30)    : wprep — Wp[d][k][i][o] fp32 -> WpT[(d*3+k)][o][i] bf16
// ---------------------------------------------------------------------------
__global__ __launch_bounds__(256) void prep_kernel(const float* __restrict__ E,
                                                   const float* __restrict__ x,
                                                   const float* __restrict__ Wp,
                                                   ushort_t* __restrict__ Ab,
                                                   ushort_t* __restrict__ xT,
                                                   ushort_t* __restrict__ xN,
                                                   ushort_t* __restrict__ WpT) {
    const int bid = blockIdx.x;
    const int tid = threadIdx.x;

    __shared__ float tb[64][68];
    __shared__ float red[8];

    if (bid < NN) {
        // ---- supports row n = bid ----
        const int n = bid;
        float en[ED];
#pragma unroll
        for (int d = 0; d < ED; ++d) en[d] = E[n * ED + d];

        float sv[NN / 256];
        float lmax = 0.0f;  // relu >= 0
#pragma unroll
        for (int j = 0; j < NN / 256; ++j) {
            const int m = tid + j * 256;
            const float* Em = E + m * ED;
            float dot = 0.0f;
#pragma unroll
            for (int d = 0; d < ED; ++d) dot += en[d] * Em[d];
            float s = fmaxf(dot, 0.0f);
            sv[j] = s;
            lmax = fmaxf(lmax, s);
        }
#pragma unroll
        for (int off = 32; off > 0; off >>= 1) lmax = fmaxf(lmax, __shfl_down(lmax, off, 64));
        if ((tid & 63) == 0) red[tid >> 6] = lmax;
        __syncthreads();
        const float bmax = fmaxf(fmaxf(red[0], red[1]), fmaxf(red[2], red[3]));

        float lsum = 0.0f;
#pragma unroll
        for (int j = 0; j < NN / 256; ++j) {
            sv[j] = __expf(sv[j] - bmax);
            lsum += sv[j];
        }
#pragma unroll
        for (int off = 32; off > 0; off >>= 1) lsum += __shfl_down(lsum, off, 64);
        if ((tid & 63) == 0) red[4 + (tid >> 6)] = lsum;
        __syncthreads();
        const float inv = 1.0f / (red[4] + red[5] + red[6] + red[7]);

#pragma unroll
        for (int j = 0; j < NN / 256; ++j) {
            Ab[(size_t)n * NN + tid + j * 256] = f2bf(sv[j] * inv);
        }
    } else if (bid < 2 * NN) {
        // ---- transpose tile ----
        const int t = bid - NN;
        const int n0 = (t & 31) * 64;
        const int b = t >> 5;

#pragma unroll
        for (int l = 0; l < 4; ++l) {
            const int idx = tid + l * 256;
            const int nn = idx >> 4;
            const int c4 = (idx & 15) << 2;
            const float4 v = *(const float4*)(x + ((size_t)b * NN + n0 + nn) * CC + c4);
            tb[c4 + 0][nn] = v.x;
            tb[c4 + 1][nn] = v.y;
            tb[c4 + 2][nn] = v.z;
            tb[c4 + 3][nn] = v.w;
        }
        __syncthreads();

#pragma unroll
        for (int l = 0; l < 2; ++l) {
            const int idx = tid + l * 256;
            const int c = idx >> 3;
            const int ch = (idx & 7) << 3;
            ushort_t pack[8];
#pragma unroll
            for (int e = 0; e < 8; ++e) pack[e] = f2bf(tb[c][ch + e]);
            *(float4*)(xT + (size_t)(b * 64 + c) * NN + n0 + ch) = *(float4*)pack;
        }
#pragma unroll
        for (int l = 0; l < 2; ++l) {
            const int idx = tid + l * 256;
            const int nn = idx >> 3;
            const int cg = (idx & 7) << 3;
            ushort_t pack[8];
#pragma unroll
            for (int e = 0; e < 8; ++e) pack[e] = f2bf(tb[cg + e][nn]);
            *(float4*)(xN + (size_t)(n0 + nn) * JJ + b * 64 + cg) = *(float4*)pack;
        }
    } else {
        // ---- wprep slice dk = bid - 2*NN ----
        const int dk = bid - 2 * NN;
        const float* src = Wp + (size_t)dk * CC * CC;

#pragma unroll
        for (int l = 0; l < 4; ++l) {
            const int idx = tid + l * 256;
            const int i = idx >> 4;
            const int o4 = (idx & 15) << 2;
            const float4 v = *(const float4*)(src + i * CC + o4);
            tb[o4 + 0][i] = v.x;
            tb[o4 + 1][i] = v.y;
            tb[o4 + 2][i] = v.z;
            tb[o4 + 3][i] = v.w;
        }
        __syncthreads();

#pragma unroll
        for (int l = 0; l < 2; ++l) {
            const int idx = tid + l * 256;
            const int o = idx >> 3;
            const int ic = (idx & 7) << 3;
            ushort_t pack[8];
#pragma unroll
            for (int e = 0; e < 8; ++e) pack[e] = f2bf(tb[o][ic + e]);
            *(float4*)(WpT + (size_t)dk * CC * CC + o * CC + ic) = *(float4*)pack;
        }
    }
}

// ---------------------------------------------------------------------------
// Kernel 2: NT-GEMM. 8 waves (512 threads) per 128x128 tile -> 4 waves/SIMD
// (was 2): grid is pinned at 512 blocks = 2 blocks/CU, so latency hiding must
// come from waves-per-block. Wave tile 32x64 (2x4 of 16x16x32). Double-
// buffered LDS (64 KB), global_load_lds(16B) + XOR swizzle, 1 barrier/iter.
//   acc[m][j] = sum_k A[m][k]*Bt[j][k]
//   MODE 0: Ct[j][m] = acc (K-major) and Cn[m][j] = acc (node-major)
//   MODE 1: Cn[m][j] = 2*acc - Zn[m][j]
// ---------------------------------------------------------------------------
template <int MODE>
__global__ __launch_bounds__(512) void gemm_nt(const ushort_t* __restrict__ A,
                                               const ushort_t* __restrict__ Bt,
                                               const ushort_t* __restrict__ Zn,
                                               ushort_t* __restrict__ Ct,
                                               ushort_t* __restrict__ Cn) {
    const int j0 = blockIdx.x * 128;
    const int m0 = blockIdx.y * 128;
    const int tid = threadIdx.x;   // 0..511
    const int lane = tid & 63;
    const int l16 = lane & 15;
    const int quad = lane >> 4;
    const int w = tid >> 6;        // wave 0..7
    const int wm = (w >> 1) * 32;  // 0,32,64,96
    const int wj = (w & 1) * 64;   // 0,64
    const int lr = lane >> 3;      // staging: row-in-group 0..7
    const int lc = lane & 7;       // staging: chunk 0..7
    const int swz = lc ^ lr;       // global chunk for this LDS slot

    __shared__ ushort_t As[2][128 * 64];  // 2 x 16 KB
    __shared__ ushort_t Bs[2][128 * 64];

    f32x4 acc[2][4];
#pragma unroll
    for (int mi = 0; mi < 2; ++mi)
#pragma unroll
        for (int ji = 0; ji < 4; ++ji) acc[mi][ji] = (f32x4){0.f, 0.f, 0.f, 0.f};

    // prefetch tile 0 into buffer 0 (each wave: 16 rows of A and of B)
#pragma unroll
    for (int inst = 0; inst < 2; ++inst) {
        const int rbase = w * 16 + inst * 8;
        const int row = rbase + lr;
        __builtin_amdgcn_global_load_lds(
            (gptr_t)(A + (size_t)(m0 + row) * NN + swz * 8),
            (lptr_t)&As[0][rbase * 64], 16, 0, 0);
        __builtin_amdgcn_global_load_lds(
            (gptr_t)(Bt + (size_t)(j0 + row) * NN + swz * 8),
            (lptr_t)&Bs[0][rbase * 64], 16, 0, 0);
    }

    for (int it = 0; it < NN / 64; ++it) {
        const int cur = it & 1;
        __syncthreads();  // drains prefetch into buf[cur]; fences buf[1-cur] readers

        if (it + 1 < NN / 64) {
            const int k0 = (it + 1) * 64;
#pragma unroll
            for (int inst = 0; inst < 2; ++inst) {
                const int rbase = w * 16 + inst * 8;
                const int row = rbase + lr;
                __builtin_amdgcn_global_load_lds(
                    (gptr_t)(A + (size_t)(m0 + row) * NN + k0 + swz * 8),
                    (lptr_t)&As[1 - cur][rbase * 64], 16, 0, 0);
                __builtin_amdgcn_global_load_lds(
                    (gptr_t)(Bt + (size_t)(j0 + row) * NN + k0 + swz * 8),
                    (lptr_t)&Bs[1 - cur][rbase * 64], 16, 0, 0);
            }
        }

#pragma unroll
        for (int ks = 0; ks < 64; ks += 32) {
            const int qb = (ks >> 3) + quad;
            short8 av[2], bv[4];
#pragma unroll
            for (int mi = 0; mi < 2; ++mi) {
                const int rA = wm + mi * 16 + l16;
                av[mi] = *(const short8*)&As[cur][rA * 64 + ((qb ^ (rA & 7)) << 3)];
            }
#pragma unroll
            for (int ji = 0; ji < 4; ++ji) {
                const int rB = wj + ji * 16 + l16;
                bv[ji] = *(const short8*)&Bs[cur][rB * 64 + ((qb ^ (rB & 7)) << 3)];
            }
#pragma unroll
            for (int mi = 0; mi < 2; ++mi)
#pragma unroll
                for (int ji = 0; ji < 4; ++ji)
                    acc[mi][ji] = __builtin_amdgcn_mfma_f32_16x16x32_bf16(
                        av[mi], bv[ji], acc[mi][ji], 0, 0, 0);
        }
    }

    // C/D layout (16x16x32): col j = lane&15, row m = quad*4 + reg.
#pragma unroll
    for (int mi = 0; mi < 2; ++mi) {
#pragma unroll
        for (int ji = 0; ji < 4; ++ji) {
            const int j = j0 + wj + ji * 16 + l16;
            const int mb = m0 + wm + mi * 16 + quad * 4;
            if (MODE == 0) {
                ushort_t o[4];
#pragma unroll
                for (int r = 0; r < 4; ++r) o[r] = f2bf(acc[mi][ji][r]);
                *(unsigned long long*)(Ct + (size_t)j * NN + mb) = *(unsigned long long*)o;
#pragma unroll
                for (int r = 0; r < 4; ++r) Cn[(size_t)(mb + r) * JJ + j] = o[r];
            } else {
#pragma unroll
                for (int r = 0; r < 4; ++r) {
                    const float z = bf2f(Zn[(size_t)(mb + r) * JJ + j]);
                    Cn[(size_t)(mb + r) * JJ + j] = f2bf(2.0f * acc[mi][ji][r] - z);
                }
            }
        }
    }
}

// ---------------------------------------------------------------------------
// Kernel 3: MFMA epilogue, 4 nodes per block (512 blocks), k-sliced.
// WpT chunks are read from L2 ONCE per block and used for all 4 nodes' W
// synthesis (L2 traffic /4 vs 1-node blocks). Wave w owns node n0+w and does
// a 64x64x64 slice-GEMM per k, accumulating across the 3 slices.
// ---------------------------------------------------------------------------
#define ONPB 4
#define OLD 72  // LDS row stride (bf16): 144 B -> 2-way bank alias (free)
__global__ __launch_bounds__(256) void out_kernel(const float* __restrict__ E,
                                                  const ushort_t* __restrict__ WpT,
                                                  const float* __restrict__ bp,
                                                  const ushort_t* __restrict__ xN,
                                                  const ushort_t* __restrict__ y1N,
                                                  const ushort_t* __restrict__ y2N,
                                                  float* __restrict__ out) {
    const int n0 = blockIdx.x * ONPB;
    const int tid = threadIdx.x;

    __shared__ ushort_t xg[ONPB][CC * OLD];  // 36.9 KB: xg[nl][b][i] per slice
    __shared__ ushort_t Wt[ONPB][CC * OLD];  // 36.9 KB: Wt[nl][o][i] per slice
    __shared__ float es[ONPB][ED];
    __shared__ float bias_s[ONPB][CC];

    if (tid < ONPB * ED) es[tid / ED][tid % ED] = E[(size_t)(n0 + tid / ED) * ED + tid % ED];
    __syncthreads();

    {   // bias for all 4 nodes: thread t -> node t>>6, o t&63
        const int nl = tid >> 6;
        const int o = tid & 63;
        float b = 0.0f;
#pragma unroll
        for (int d = 0; d < ED; ++d) b += es[nl][d] * bp[d * CC + o];
        bias_s[nl][o] = b;
    }

    const int lane = tid & 63;
    const int l16 = lane & 15;
    const int quad = lane >> 4;
    const int w = tid >> 6;  // wave == local node index

    f32x4 acc[4][4];
#pragma unroll
    for (int mi = 0; mi < 4; ++mi)
#pragma unroll
        for (int ji = 0; ji < 4; ++ji) acc[mi][ji] = (f32x4){0.f, 0.f, 0.f, 0.f};

    for (int k = 0; k < KK; ++k) {
        const ushort_t* src = (k == 0) ? xN : (k == 1) ? y1N : y2N;
        __syncthreads();  // protect previous slice's LDS readers

        // stage xg: 4 nodes x 512 float4 chunks (each node row is 8 KB contiguous)
        for (int t = tid; t < ONPB * 512; t += 256) {
            const int nl = t >> 9;
            const int c = t & 511;  // b = c>>3, ic = (c&7)*8
            *(float4*)&xg[nl][(c >> 3) * OLD + ((c & 7) << 3)] =
                *(const float4*)(src + (size_t)(n0 + nl) * JJ + c * 8);
        }
        // synth Wt for 4 nodes: each WpT chunk read once, broadcast via regs
        for (int t = tid; t < 512; t += 256) {
            const int o = t >> 3;
            const int ic = (t & 7) << 3;
            float a4[ONPB][8];
#pragma unroll
            for (int nl = 0; nl < ONPB; ++nl)
#pragma unroll
                for (int e = 0; e < 8; ++e) a4[nl][e] = 0.0f;
#pragma unroll
            for (int d = 0; d < ED; ++d) {
                const float4 p = *(const float4*)(WpT + ((size_t)(d * KK + k) * CC + o) * CC + ic);
                const ushort_t* pp = (const ushort_t*)&p;
                float u[8];
#pragma unroll
                for (int e = 0; e < 8; ++e) u[e] = bf2f(pp[e]);
#pragma unroll
                for (int nl = 0; nl < ONPB; ++nl) {
                    const float ed = es[nl][d];
#pragma unroll
                    for (int e = 0; e < 8; ++e) a4[nl][e] += ed * u[e];
                }
            }
#pragma unroll
            for (int nl = 0; nl < ONPB; ++nl) {
                ushort_t pk[8];
#pragma unroll
                for (int e = 0; e < 8; ++e) pk[e] = f2bf(a4[nl][e]);
                *(float4*)&Wt[nl][o * OLD + ic] = *(float4*)pk;
            }
        }
        __syncthreads();

        // wave w: node w's [64b x 64i] @ [64i x 64o] slice
#pragma unroll
        for (int ks = 0; ks < 64; ks += 32) {
            short8 av[4], bv[4];
#pragma unroll
            for (int mi = 0; mi < 4; ++mi)
                av[mi] = *(const short8*)&xg[w][(mi * 16 + l16) * OLD + ks + quad * 8];
#pragma unroll
            for (int ji = 0; ji < 4; ++ji)
                bv[ji] = *(const short8*)&Wt[w][(ji * 16 + l16) * OLD + ks + quad * 8];
#pragma unroll
            for (int mi = 0; mi < 4; ++mi)
#pragma unroll
                for (int ji = 0; ji < 4; ++ji)
                    acc[mi][ji] = __builtin_amdgcn_mfma_f32_16x16x32_bf16(
                        av[mi], bv[ji], acc[mi][ji], 0, 0, 0);
        }
    }

    // C/D: col o = l16 + 16*ji, row b = mi*16 + quad*4 + r. 64 B stores.
    const int n = n0 + w;
#pragma unroll
    for (int mi = 0; mi < 4; ++mi) {
#pragma unroll
        for (int ji = 0; ji < 4; ++ji) {
            const int o = ji * 16 + l16;
            const float bo = bias_s[w][o];
#pragma unroll
            for (int r = 0; r < 4; ++r) {
                const int b = mi * 16 + quad * 4 + r;
                out[((size_t)b * NN + n) * CC + o] = acc[mi][ji][r] + bo;
            }
        }
    }
}
#undef OLD
#undef ONPB

// ---------------------------------------------------------------------------
// Host launch: 4 dispatches total.
// Workspace (bf16): Ab 8 | xT 16 | xN 16 | y1T 16 | y1N 16 | y2N 16 | WpT 0.24
//   = 88.25 MB.
// ---------------------------------------------------------------------------
extern "C" void kernel_launch(void* const* d_in, const int* in_sizes, int n_in,
                              void* d_out, int out_size, void* d_ws, size_t ws_size,
                              hipStream_t stream) {
    const float* x  = (const float*)d_in[0];
    const float* E  = (const float*)d_in[1];
    const float* Wp = (const float*)d_in[2];
    const float* bp = (const float*)d_in[3];

    ushort_t* Ab  = (ushort_t*)d_ws;                    // [2048][2048]
    ushort_t* xT  = Ab + (size_t)NN * NN;               // [4096][2048]
    ushort_t* xN  = xT + (size_t)JJ * NN;               // [2048][4096]
    ushort_t* y1T = xN + (size_t)NN * JJ;               // [4096][2048]
    ushort_t* y1N = y1T + (size_t)JJ * NN;              // [2048][4096]
    ushort_t* y2N = y1N + (size_t)NN * JJ;              // [2048][4096]
    ushort_t* WpT = y2N + (size_t)NN * JJ;              // [30][64][64]
    float* out = (float*)d_out;

    prep_kernel<<<2 * NN + ED * KK, 256, 0, stream>>>(E, x, Wp, Ab, xT, xN, WpT);
    // y1 = A @ x : dual output (K-major + node-major)
    gemm_nt<0><<<dim3(JJ / 128, NN / 128), 512, 0, stream>>>(Ab, xT, nullptr, y1T, y1N);
    // y2 = 2 A @ y1 - x : node-major only
    gemm_nt<1><<<dim3(JJ / 128, NN / 128), 512, 0, stream>>>(Ab, y1T, xN, nullptr, y2N);
    out_kernel<<<NN / 4, 256, 0, stream>>>(E, WpT, bp, xN, y1N, y2N, out);
}

// Round 8
// 223.962 us; speedup vs baseline: 1.0383x; 1.0383x over previous
//
#include <hip/hip_runtime.h>

// B=64, N=2048, DIM_IN=DIM_OUT=64, CHEB_K=3, EMBED_DIM=10
#define NN 2048
#define BB 64
#define CC 64
#define ED 10
#define KK 3
#define JJ (BB * CC)   // 4096

typedef unsigned short ushort_t;
typedef __attribute__((ext_vector_type(8))) short short8;   // 8 bf16 = 4 VGPRs
typedef __attribute__((ext_vector_type(4))) float f32x4;

typedef const __attribute__((address_space(1))) unsigned* gptr_t;
typedef __attribute__((address_space(3))) unsigned* lptr_t;

static __device__ __forceinline__ ushort_t f2bf(float f) {
    union { float f; unsigned u; } x{f};
    unsigned r = x.u + 0x7FFF + ((x.u >> 16) & 1);  // RTN-even
    return (ushort_t)(r >> 16);
}
static __device__ __forceinline__ float bf2f(ushort_t h) {
    union { unsigned u; float f; } x;
    x.u = ((unsigned)h) << 16;
    return x.f;
}

// ---------------------------------------------------------------------------
// Kernel 1 (merged prep): blockIdx selects role.
//   [0, NN)            : supports — A_bf16[n][m] = softmax(relu(E E^T)) row n
//   [NN, 2*NN)         : transpose — x[b][n][c] -> xT[(b*64+c)][n], xN[n][j]
//   [2*NN, 2*NN+30)    : wprep — Wp[d][k][i][o] fp32 -> WpT[(d*3+k)][o][i] bf16
// ---------------------------------------------------------------------------
__global__ __launch_bounds__(256) void prep_kernel(const float* __restrict__ E,
                                                   const float* __restrict__ x,
                                                   const float* __restrict__ Wp,
                                                   ushort_t* __restrict__ Ab,
                                                   ushort_t* __restrict__ xT,
                                                   ushort_t* __restrict__ xN,
                                                   ushort_t* __restrict__ WpT) {
    const int bid = blockIdx.x;
    const int tid = threadIdx.x;

    __shared__ float tb[64][68];
    __shared__ float red[8];

    if (bid < NN) {
        // ---- supports row n = bid ----
        const int n = bid;
        float en[ED];
#pragma unroll
        for (int d = 0; d < ED; ++d) en[d] = E[n * ED + d];

        float sv[NN / 256];
        float lmax = 0.0f;  // relu >= 0
#pragma unroll
        for (int j = 0; j < NN / 256; ++j) {
            const int m = tid + j * 256;
            const float* Em = E + m * ED;
            float dot = 0.0f;
#pragma unroll
            for (int d = 0; d < ED; ++d) dot += en[d] * Em[d];
            float s = fmaxf(dot, 0.0f);
            sv[j] = s;
            lmax = fmaxf(lmax, s);
        }
#pragma unroll
        for (int off = 32; off > 0; off >>= 1) lmax = fmaxf(lmax, __shfl_down(lmax, off, 64));
        if ((tid & 63) == 0) red[tid >> 6] = lmax;
        __syncthreads();
        const float bmax = fmaxf(fmaxf(red[0], red[1]), fmaxf(red[2], red[3]));

        float lsum = 0.0f;
#pragma unroll
        for (int j = 0; j < NN / 256; ++j) {
            sv[j] = __expf(sv[j] - bmax);
            lsum += sv[j];
        }
#pragma unroll
        for (int off = 32; off > 0; off >>= 1) lsum += __shfl_down(lsum, off, 64);
        if ((tid & 63) == 0) red[4 + (tid >> 6)] = lsum;
        __syncthreads();
        const float inv = 1.0f / (red[4] + red[5] + red[6] + red[7]);

#pragma unroll
        for (int j = 0; j < NN / 256; ++j) {
            Ab[(size_t)n * NN + tid + j * 256] = f2bf(sv[j] * inv);
        }
    } else if (bid < 2 * NN) {
        // ---- transpose tile ----
        const int t = bid - NN;
        const int n0 = (t & 31) * 64;
        const int b = t >> 5;

#pragma unroll
        for (int l = 0; l < 4; ++l) {
            const int idx = tid + l * 256;
            const int nn = idx >> 4;
            const int c4 = (idx & 15) << 2;
            const float4 v = *(const float4*)(x + ((size_t)b * NN + n0 + nn) * CC + c4);
            tb[c4 + 0][nn] = v.x;
            tb[c4 + 1][nn] = v.y;
            tb[c4 + 2][nn] = v.z;
            tb[c4 + 3][nn] = v.w;
        }
        __syncthreads();

#pragma unroll
        for (int l = 0; l < 2; ++l) {
            const int idx = tid + l * 256;
            const int c = idx >> 3;
            const int ch = (idx & 7) << 3;
            ushort_t pack[8];
#pragma unroll
            for (int e = 0; e < 8; ++e) pack[e] = f2bf(tb[c][ch + e]);
            *(float4*)(xT + (size_t)(b * 64 + c) * NN + n0 + ch) = *(float4*)pack;
        }
#pragma unroll
        for (int l = 0; l < 2; ++l) {
            const int idx = tid + l * 256;
            const int nn = idx >> 3;
            const int cg = (idx & 7) << 3;
            ushort_t pack[8];
#pragma unroll
            for (int e = 0; e < 8; ++e) pack[e] = f2bf(tb[cg + e][nn]);
            *(float4*)(xN + (size_t)(n0 + nn) * JJ + b * 64 + cg) = *(float4*)pack;
        }
    } else {
        // ---- wprep slice dk = bid - 2*NN ----
        const int dk = bid - 2 * NN;
        const float* src = Wp + (size_t)dk * CC * CC;

#pragma unroll
        for (int l = 0; l < 4; ++l) {
            const int idx = tid + l * 256;
            const int i = idx >> 4;
            const int o4 = (idx & 15) << 2;
            const float4 v = *(const float4*)(src + i * CC + o4);
            tb[o4 + 0][i] = v.x;
            tb[o4 + 1][i] = v.y;
            tb[o4 + 2][i] = v.z;
            tb[o4 + 3][i] = v.w;
        }
        __syncthreads();

#pragma unroll
        for (int l = 0; l < 2; ++l) {
            const int idx = tid + l * 256;
            const int o = idx >> 3;
            const int ic = (idx & 7) << 3;
            ushort_t pack[8];
#pragma unroll
            for (int e = 0; e < 8; ++e) pack[e] = f2bf(tb[o][ic + e]);
            *(float4*)(WpT + (size_t)dk * CC * CC + o * CC + ic) = *(float4*)pack;
        }
    }
}

// ---------------------------------------------------------------------------
// Kernel 2: NT-GEMM. 8 waves (512 threads) per 128x128 tile, wave tile 32x64.
// Double-buffered LDS (64 KB), global_load_lds(16B) + XOR swizzle, 1
// barrier/iter. (Round-7 measurement: ~neutral vs 4-wave; kept.)
//   acc[m][j] = sum_k A[m][k]*Bt[j][k]
//   MODE 0: Ct[j][m] = acc (K-major) and Cn[m][j] = acc (node-major)
//   MODE 1: Cn[m][j] = 2*acc - Zn[m][j]
// ---------------------------------------------------------------------------
template <int MODE>
__global__ __launch_bounds__(512) void gemm_nt(const ushort_t* __restrict__ A,
                                               const ushort_t* __restrict__ Bt,
                                               const ushort_t* __restrict__ Zn,
                                               ushort_t* __restrict__ Ct,
                                               ushort_t* __restrict__ Cn) {
    const int j0 = blockIdx.x * 128;
    const int m0 = blockIdx.y * 128;
    const int tid = threadIdx.x;   // 0..511
    const int lane = tid & 63;
    const int l16 = lane & 15;
    const int quad = lane >> 4;
    const int w = tid >> 6;        // wave 0..7
    const int wm = (w >> 1) * 32;  // 0,32,64,96
    const int wj = (w & 1) * 64;   // 0,64
    const int lr = lane >> 3;      // staging: row-in-group 0..7
    const int lc = lane & 7;       // staging: chunk 0..7
    const int swz = lc ^ lr;       // global chunk for this LDS slot

    __shared__ ushort_t As[2][128 * 64];  // 2 x 16 KB
    __shared__ ushort_t Bs[2][128 * 64];

    f32x4 acc[2][4];
#pragma unroll
    for (int mi = 0; mi < 2; ++mi)
#pragma unroll
        for (int ji = 0; ji < 4; ++ji) acc[mi][ji] = (f32x4){0.f, 0.f, 0.f, 0.f};

    // prefetch tile 0 into buffer 0 (each wave: 16 rows of A and of B)
#pragma unroll
    for (int inst = 0; inst < 2; ++inst) {
        const int rbase = w * 16 + inst * 8;
        const int row = rbase + lr;
        __builtin_amdgcn_global_load_lds(
            (gptr_t)(A + (size_t)(m0 + row) * NN + swz * 8),
            (lptr_t)&As[0][rbase * 64], 16, 0, 0);
        __builtin_amdgcn_global_load_lds(
            (gptr_t)(Bt + (size_t)(j0 + row) * NN + swz * 8),
            (lptr_t)&Bs[0][rbase * 64], 16, 0, 0);
    }

    for (int it = 0; it < NN / 64; ++it) {
        const int cur = it & 1;
        __syncthreads();  // drains prefetch into buf[cur]; fences buf[1-cur] readers

        if (it + 1 < NN / 64) {
            const int k0 = (it + 1) * 64;
#pragma unroll
            for (int inst = 0; inst < 2; ++inst) {
                const int rbase = w * 16 + inst * 8;
                const int row = rbase + lr;
                __builtin_amdgcn_global_load_lds(
                    (gptr_t)(A + (size_t)(m0 + row) * NN + k0 + swz * 8),
                    (lptr_t)&As[1 - cur][rbase * 64], 16, 0, 0);
                __builtin_amdgcn_global_load_lds(
                    (gptr_t)(Bt + (size_t)(j0 + row) * NN + k0 + swz * 8),
                    (lptr_t)&Bs[1 - cur][rbase * 64], 16, 0, 0);
            }
        }

#pragma unroll
        for (int ks = 0; ks < 64; ks += 32) {
            const int qb = (ks >> 3) + quad;
            short8 av[2], bv[4];
#pragma unroll
            for (int mi = 0; mi < 2; ++mi) {
                const int rA = wm + mi * 16 + l16;
                av[mi] = *(const short8*)&As[cur][rA * 64 + ((qb ^ (rA & 7)) << 3)];
            }
#pragma unroll
            for (int ji = 0; ji < 4; ++ji) {
                const int rB = wj + ji * 16 + l16;
                bv[ji] = *(const short8*)&Bs[cur][rB * 64 + ((qb ^ (rB & 7)) << 3)];
            }
#pragma unroll
            for (int mi = 0; mi < 2; ++mi)
#pragma unroll
                for (int ji = 0; ji < 4; ++ji)
                    acc[mi][ji] = __builtin_amdgcn_mfma_f32_16x16x32_bf16(
                        av[mi], bv[ji], acc[mi][ji], 0, 0, 0);
        }
    }

    // C/D layout (16x16x32): col j = lane&15, row m = quad*4 + reg.
#pragma unroll
    for (int mi = 0; mi < 2; ++mi) {
#pragma unroll
        for (int ji = 0; ji < 4; ++ji) {
            const int j = j0 + wj + ji * 16 + l16;
            const int mb = m0 + wm + mi * 16 + quad * 4;
            if (MODE == 0) {
                ushort_t o[4];
#pragma unroll
                for (int r = 0; r < 4; ++r) o[r] = f2bf(acc[mi][ji][r]);
                *(unsigned long long*)(Ct + (size_t)j * NN + mb) = *(unsigned long long*)o;
#pragma unroll
                for (int r = 0; r < 4; ++r) Cn[(size_t)(mb + r) * JJ + j] = o[r];
            } else {
#pragma unroll
                for (int r = 0; r < 4; ++r) {
                    const float z = bf2f(Zn[(size_t)(mb + r) * JJ + j]);
                    Cn[(size_t)(mb + r) * JJ + j] = f2bf(2.0f * acc[mi][ji][r] - z);
                }
            }
        }
    }
}

// ---------------------------------------------------------------------------
// Kernel 3: MFMA epilogue v3. One node per block, 4 waves.
// - A-fragments (xg rows) loaded DIRECTLY from global into registers (no LDS):
//   wave w owns b-rows w*16..w*16+15; av[kc] = src[kc>>1][n][b*64 + kc*32-part].
//   Issued before the synth barrier -> deep in flight while VALU synthesizes W.
// - LDS holds only Wt[o][ki] (25.6 KB) + bias -> 5-6 blocks/CU (20+ waves/CU),
//   vs round-7's 75 KB / 2 blocks/CU which left HBM at 1 TB/s.
// ---------------------------------------------------------------------------
#define OLD 200  // Wt row stride (bf16 elems)
__global__ __launch_bounds__(256, 4) void out_kernel(const float* __restrict__ E,
                                                     const ushort_t* __restrict__ WpT,
                                                     const float* __restrict__ bp,
                                                     const ushort_t* __restrict__ xN,
                                                     const ushort_t* __restrict__ y1N,
                                                     const ushort_t* __restrict__ y2N,
                                                     float* __restrict__ out) {
    const int n = blockIdx.x;
    const int tid = threadIdx.x;
    const int lane = tid & 63;
    const int l16 = lane & 15;
    const int quad = lane >> 4;
    const int w = tid >> 6;  // wave 0..3 -> b-rows w*16..+15

    __shared__ ushort_t Wt[CC * OLD];  // 25.6 KB: Wt[o][k*64+i]
    __shared__ float es[ED];
    __shared__ float bias_s[CC];

    if (tid < ED) es[tid] = E[n * ED + tid];

    // direct-global A fragments: A[m=l16][k=quad*8+j], ki = kc*32 + quad*8
    short8 av[6];
    {
        const ushort_t* s0 = xN + (size_t)n * JJ + (w * 16 + l16) * 64;
        const ushort_t* s1 = y1N + (size_t)n * JJ + (w * 16 + l16) * 64;
        const ushort_t* s2 = y2N + (size_t)n * JJ + (w * 16 + l16) * 64;
        av[0] = *(const short8*)(s0 + quad * 8);
        av[1] = *(const short8*)(s0 + 32 + quad * 8);
        av[2] = *(const short8*)(s1 + quad * 8);
        av[3] = *(const short8*)(s1 + 32 + quad * 8);
        av[4] = *(const short8*)(s2 + quad * 8);
        av[5] = *(const short8*)(s2 + 32 + quad * 8);
    }
    __syncthreads();  // es visible

    float en[ED];
#pragma unroll
    for (int d = 0; d < ED; ++d) en[d] = es[d];

    if (tid < CC) {
        float bsum = 0.0f;
#pragma unroll
        for (int d = 0; d < ED; ++d) bsum += en[d] * bp[d * CC + tid];
        bias_s[tid] = bsum;
    }

    // synthesize Wt[o][ki] bf16: 1536 chunks of 8 i-elems, fp32 accum over d
    for (int t = tid; t < CC * 24; t += 256) {
        const int o = t / 24;
        const int kc8 = t % 24;           // k = kc8>>3, i-chunk = kc8&7
        const int k = kc8 >> 3;
        const int ic = (kc8 & 7) << 3;
        float s[8];
#pragma unroll
        for (int e = 0; e < 8; ++e) s[e] = 0.0f;
#pragma unroll
        for (int d = 0; d < ED; ++d) {
            const float4 wv4 = *(const float4*)(WpT + ((size_t)(d * KK + k) * CC + o) * CC + ic);
            const ushort_t* wp = (const ushort_t*)&wv4;
#pragma unroll
            for (int e = 0; e < 8; ++e) s[e] += en[d] * bf2f(wp[e]);
        }
        ushort_t pack[8];
#pragma unroll
        for (int e = 0; e < 8; ++e) pack[e] = f2bf(s[e]);
        *(float4*)&Wt[o * OLD + kc8 * 8] = *(float4*)pack;
    }
    __syncthreads();

    f32x4 acc[4];
#pragma unroll
    for (int ji = 0; ji < 4; ++ji) acc[ji] = (f32x4){0.f, 0.f, 0.f, 0.f};

#pragma unroll
    for (int kc = 0; kc < 6; ++kc) {  // K = 192 = 6 x 32
#pragma unroll
        for (int ji = 0; ji < 4; ++ji) {
            const short8 bv = *(const short8*)&Wt[(ji * 16 + l16) * OLD + kc * 32 + quad * 8];
            acc[ji] = __builtin_amdgcn_mfma_f32_16x16x32_bf16(av[kc], bv, acc[ji], 0, 0, 0);
        }
    }

    // C/D: col o = l16 + 16*ji, row b = w*16 + quad*4 + r.
#pragma unroll
    for (int ji = 0; ji < 4; ++ji) {
        const int o = ji * 16 + l16;
        const float bo = bias_s[o];
#pragma unroll
        for (int r = 0; r < 4; ++r) {
            const int b = w * 16 + quad * 4 + r;
            out[((size_t)b * NN + n) * CC + o] = acc[ji][r] + bo;
        }
    }
}
#undef OLD

// ---------------------------------------------------------------------------
// Host launch: 4 dispatches total.
// Workspace (bf16): Ab 8 | xT 16 | xN 16 | y1T 16 | y1N 16 | y2N 16 | WpT 0.24
//   = 88.25 MB.
// ---------------------------------------------------------------------------
extern "C" void kernel_launch(void* const* d_in, const int* in_sizes, int n_in,
                              void* d_out, int out_size, void* d_ws, size_t ws_size,
                              hipStream_t stream) {
    const float* x  = (const float*)d_in[0];
    const float* E  = (const float*)d_in[1];
    const float* Wp = (const float*)d_in[2];
    const float* bp = (const float*)d_in[3];

    ushort_t* Ab  = (ushort_t*)d_ws;                    // [2048][2048]
    ushort_t* xT  = Ab + (size_t)NN * NN;               // [4096][2048]
    ushort_t* xN  = xT + (size_t)JJ * NN;               // [2048][4096]
    ushort_t* y1T = xN + (size_t)NN * JJ;               // [4096][2048]
    ushort_t* y1N = y1T + (size_t)JJ * NN;              // [2048][4096]
    ushort_t* y2N = y1N + (size_t)NN * JJ;              // [2048][4096]
    ushort_t* WpT = y2N + (size_t)NN * JJ;              // [30][64][64]
    float* out = (float*)d_out;

    prep_kernel<<<2 * NN + ED * KK, 256, 0, stream>>>(E, x, Wp, Ab, xT, xN, WpT);
    // y1 = A @ x : dual output (K-major + node-major)
    gemm_nt<0><<<dim3(JJ / 128, NN / 128), 512, 0, stream>>>(Ab, xT, nullptr, y1T, y1N);
    // y2 = 2 A @ y1 - x : node-major only
    gemm_nt<1><<<dim3(JJ / 128, NN / 128), 512, 0, stream>>>(Ab, y1T, xN, nullptr, y2N);
    out_kernel<<<NN, 256, 0, stream>>>(E, WpT, bp, xN, y1N, y2N, out);
}